// Round 5
// baseline (289.379 us; speedup 1.0000x reference)
//
#include <hip/hip_runtime.h>

typedef unsigned short u16;
typedef __attribute__((ext_vector_type(4))) unsigned short u16x4;
typedef __attribute__((ext_vector_type(8))) unsigned short u16x8;
typedef __attribute__((ext_vector_type(8))) __bf16 bf16x8;
typedef __attribute__((ext_vector_type(4))) float f32x4;

#define N_BANK  50000
#define NPAD    50048      // 782 * 64
#define NCHUNKS 782        // 64-row chunks
#define NCPAD   832        // 13 * 64 rounds in pass 2
#define SEGS    64
#define DIM     128
#define NQ      4096
#define CHUNK_B 16384      // 64 rows * 128 dims * 2B

// ---- workspace layout (byte offsets). minbuf dtype gated on ws_size. ----
#define WS_BANKBF 0u          // NPAD*128*2  = 12,812,288
#define WS_B2     12812288u   // NPAD*4      =    200,192
#define WS_QBF    13012480u   // 4096*128*2  =  1,048,576
#define WS_Q2     14061056u   // 4096*4      =     16,384
#define WS_SCORES 14077440u   // 4096*4      =     16,384
#define WS_MINBUF 14093824u   // fp32: 832*4096*4 = 13,631,488 (end 27,725,312)
                              // bf16: 832*4096*2 =  6,815,744 (end 20,909,568)
#define WS_NEED_F32 27725312u

__device__ __forceinline__ u16 f2bf(float f) {
  unsigned int x = __float_as_uint(f);
  x += 0x7fffu + ((x >> 16) & 1u);   // RNE to bf16
  return (u16)(x >> 16);
}
__device__ __forceinline__ u16 f2bf_up(float f) {  // round toward +inf (conservative min)
  unsigned int b = __float_as_uint(f);
  u16 h = (u16)(b >> 16);
  if (!(b >> 31) && (b & 0xffffu)) h++;
  return h;
}
__device__ __forceinline__ float bf2f(u16 h) {
  return __uint_as_float(((unsigned int)h) << 16);
}

// sorted-ascending top-5 insert, SAFE for x >= T4 (then it's a no-op).
#define SINS5(T0, T1, T2, T3, T4, x)                                  \
  {                                                                   \
    bool c3 = (x) < T3, c2 = (x) < T2, c1 = (x) < T1, c0 = (x) < T0;  \
    float nx_ = fminf((x), T4);                                       \
    T4 = c3 ? T3 : nx_;                                               \
    T3 = c3 ? (c2 ? T2 : (x)) : T3;                                   \
    T2 = c2 ? (c1 ? T1 : (x)) : T2;                                   \
    T1 = c1 ? (c0 ? T0 : (x)) : T1;                                   \
    T0 = c0 ? (x) : T0;                                               \
  }

__device__ __forceinline__ void gload_lds16(const void* g, void* l) {
  __builtin_amdgcn_global_load_lds(
      (const __attribute__((address_space(1))) void*)g,
      (__attribute__((address_space(3))) void*)l, 16, 0, 0);
}

// ---------- prep: bank -> bf16 (+ pad rows), b2 = ||b||^2 (pad = 1e30) ----------
__global__ __launch_bounds__(256) void prep_bank(const float* __restrict__ bank,
                                                 u16* __restrict__ bb,
                                                 float* __restrict__ b2) {
  int row = blockIdx.x * 8 + (threadIdx.x >> 5);
  int cc  = threadIdx.x & 31;
  bool valid = row < N_BANK;
  f32x4 v = f32x4{0.f, 0.f, 0.f, 0.f};
  if (valid) v = *reinterpret_cast<const f32x4*>(bank + (size_t)row * DIM + cc * 4);
  float s = v.x * v.x + v.y * v.y + v.z * v.z + v.w * v.w;
#pragma unroll
  for (int o = 16; o > 0; o >>= 1) s += __shfl_xor(s, o, 32);
  u16x4 u;
  u.x = f2bf(v.x); u.y = f2bf(v.y); u.z = f2bf(v.z); u.w = f2bf(v.w);
  *reinterpret_cast<u16x4*>(bb + (size_t)row * DIM + cc * 4) = u;
  if (cc == 0) b2[row] = valid ? s : 1e30f;
}

// ---------- prep: embeddings [4,128,32,32] -> q_bf16 [4096][128], q2 ----------
__global__ __launch_bounds__(256) void prep_q(const float* __restrict__ emb,
                                              u16* __restrict__ qb,
                                              float* __restrict__ q2) {
  int q = blockIdx.x * 256 + threadIdx.x;
  int b = q >> 10, yx = q & 1023;
  const float* src = emb + (size_t)b * 131072 + yx;
  float s = 0.f;
#pragma unroll
  for (int d0 = 0; d0 < 16; ++d0) {
    u16x8 u;
#pragma unroll
    for (int j = 0; j < 8; ++j) {
      float v = src[(d0 * 8 + j) * 1024];
      s += v * v;
      u[j] = f2bf(v);
    }
    *reinterpret_cast<u16x8*>(qb + (size_t)q * DIM + d0 * 8) = u;
  }
  q2[q] = s;
}

// ---------- pass 1: GEMM + per-(query, chunk) MIN of s = b2 - 2*dot ----------
// grid 2048 = 32 qgroups (128 q) x 64 segments; block 256 thr = 4 waves.
// wave owns 32 queries (2 subgroups of 16); minbuf layout [chunk][query].
template <bool MF32>
__global__ __launch_bounds__(256) void pass1_kernel(const u16* __restrict__ bankbf,
                                                    const float* __restrict__ b2,
                                                    const u16* __restrict__ qbf,
                                                    void* __restrict__ minbuf) {
  __shared__ char smc[2 * CHUNK_B];   // 32KB double buffer
  const int tid = threadIdx.x;
  const int w   = tid >> 6;
  const int l   = tid & 63;
  const int l15 = l & 15, lhi = l >> 4;
  const int qgi = blockIdx.x & 31;
  const int seg = blockIdx.x >> 5;
  const int qbase = qgi * 128 + w * 32;

  bf16x8 bqA[4], bqB[4];
  {
    const u16* qa = qbf + (size_t)(qbase + l15) * DIM + lhi * 8;
#pragma unroll
    for (int kk = 0; kk < 4; ++kk) {
      bqA[kk] = *reinterpret_cast<const bf16x8*>(qa + kk * 32);
      bqB[kk] = *reinterpret_cast<const bf16x8*>(qa + 16 * DIM + kk * 32);
    }
  }

  auto stage = [&](int cc, int buf) {
    const char* gb = (const char*)bankbf + (size_t)cc * CHUNK_B;
#pragma unroll
    for (int i = 0; i < 4; ++i) {
      int x  = i * 4096 + tid * 16;
      int sx = x ^ (((x >> 8) & 7) << 4);     // XOR-swizzle on SOURCE, dest linear
      gload_lds16(gb + sx, smc + buf * CHUNK_B + i * 4096 + w * 1024);
    }
  };

  stage(seg, 0);
  __syncthreads();
  int cur = 0;

  for (int c = seg; c < NCHUNKS; c += SEGS) {
    if (c + SEGS < NCHUNKS) stage(c + SEGS, cur ^ 1);
    const char* sb = smc + cur * CHUNK_B;
    float mA = 3e38f, mB = 3e38f;
#pragma unroll
    for (int t = 0; t < 4; ++t) {
      f32x4 b2v = *reinterpret_cast<const f32x4*>(b2 + c * 64 + t * 16 + lhi * 4);
      bf16x8 af[4];
#pragma unroll
      for (int kk = 0; kk < 4; ++kk) {
        int p  = (t * 16 + l15) * 256 + kk * 64 + lhi * 16;
        int ph = p ^ (((p >> 8) & 7) << 4);   // swizzled read
        af[kk] = *reinterpret_cast<const bf16x8*>(sb + ph);
      }
      f32x4 accA = f32x4{0.f, 0.f, 0.f, 0.f};
      f32x4 accB = f32x4{0.f, 0.f, 0.f, 0.f};
#pragma unroll
      for (int kk = 0; kk < 4; ++kk) {
        accA = __builtin_amdgcn_mfma_f32_16x16x32_bf16(af[kk], bqA[kk], accA, 0, 0, 0);
        accB = __builtin_amdgcn_mfma_f32_16x16x32_bf16(af[kk], bqB[kk], accB, 0, 0, 0);
      }
#pragma unroll
      for (int j = 0; j < 4; ++j) {
        mA = fminf(mA, fmaf(-2.f, accA[j], b2v[j]));
        mB = fminf(mB, fmaf(-2.f, accB[j], b2v[j]));
      }
    }
    // pool the 4 lane-groups (rows) per query
    mA = fminf(mA, __shfl_xor(mA, 16)); mA = fminf(mA, __shfl_xor(mA, 32));
    mB = fminf(mB, __shfl_xor(mB, 16)); mB = fminf(mB, __shfl_xor(mB, 32));
    if (l < 16) {
      if (MF32) {
        float* mb = (float*)minbuf + (size_t)c * NQ + qbase;
        mb[l] = mA; mb[16 + l] = mB;
      } else {
        u16* mb = (u16*)minbuf + (size_t)c * NQ + qbase;
        mb[l] = f2bf_up(mA); mb[16 + l] = f2bf_up(mB);
      }
    }
    __syncthreads();
    cur ^= 1;
  }
}

// ---------- pass 2: per query, m5 of chunk-mins -> rescan flagged chunks ----------
// grid 1024 x 256: one wave per query.
template <bool MF32>
__global__ __launch_bounds__(256) void pass2_kernel(const u16* __restrict__ bankbf,
                                                    const float* __restrict__ b2,
                                                    const u16* __restrict__ qbf,
                                                    const float* __restrict__ q2,
                                                    const void* __restrict__ minbuf,
                                                    float* __restrict__ scores) {
  const int w = threadIdx.x >> 6, l = threadIdx.x & 63;
  const int q = blockIdx.x * 4 + w;

  // query fragments (bf16, same values the MFMA consumed)
  u16x8 qu[16];
#pragma unroll
  for (int g = 0; g < 16; ++g)
    qu[g] = *reinterpret_cast<const u16x8*>(qbf + (size_t)q * DIM + g * 8);

  // top-5 of the 782 chunk-mins (lane l handles chunks l, l+64, ...)
  float T0 = 3e38f, T1 = 3e38f, T2 = 3e38f, T3 = 3e38f, T4 = 3e38f;
  for (int r = 0; r < 13; ++r) {
    int c = r * 64 + l;
    float vr = 3e38f;
    if (c < NCHUNKS) {
      vr = MF32 ? ((const float*)minbuf)[(size_t)c * NQ + q]
                : bf2f(((const u16*)minbuf)[(size_t)c * NQ + q]);
    }
    SINS5(T0, T1, T2, T3, T4, vr);
  }
  // butterfly merge across 64 lanes (disjoint halves at each stage)
#pragma unroll
  for (int s = 1; s < 64; s <<= 1) {
    float p0 = __shfl_xor(T0, s), p1 = __shfl_xor(T1, s), p2 = __shfl_xor(T2, s),
          p3 = __shfl_xor(T3, s), p4 = __shfl_xor(T4, s);
    SINS5(T0, T1, T2, T3, T4, p0);
    SINS5(T0, T1, T2, T3, T4, p1);
    SINS5(T0, T1, T2, T3, T4, p2);
    SINS5(T0, T1, T2, T3, T4, p3);
    SINS5(T0, T1, T2, T3, T4, p4);
  }
  // threshold: 5th-smallest chunk-min + slack (bf16 ulps / MFMA-vs-serial rounding)
  const float thr = T4 + fabsf(T4) * (MF32 ? 2e-4f : 0.01f) + 0.02f;

  // rescan flagged chunks exactly; maintain final top-5 per lane
  float F0 = 3e38f, F1 = 3e38f, F2 = 3e38f, F3 = 3e38f, F4 = 3e38f;
  for (int r = 0; r < 13; ++r) {
    int c0 = r * 64 + l;
    float vr = 3e38f;
    if (c0 < NCHUNKS) {
      vr = MF32 ? ((const float*)minbuf)[(size_t)c0 * NQ + q]
                : bf2f(((const u16*)minbuf)[(size_t)c0 * NQ + q]);
    }
    unsigned long long mset = __ballot(vr <= thr);
    while (mset) {                     // wave-uniform candidate loop
      int bit = __ffsll((long long)mset) - 1;
      mset &= mset - 1;
      int row = (r * 64 + bit) * 64 + l;   // 64 lanes = 64 rows of chunk
      const u16x8* bp = (const u16x8*)(bankbf + (size_t)row * DIM);
      float dot = 0.f;
#pragma unroll
      for (int g = 0; g < 16; ++g) {
        u16x8 bb = bp[g];
#pragma unroll
        for (int e = 0; e < 8; ++e)
          dot = fmaf(bf2f(bb[e]), bf2f(qu[g][e]), dot);
      }
      float d = fmaf(-2.f, dot, b2[row]);
      SINS5(F0, F1, F2, F3, F4, d);
    }
  }
  // merge final top-5 across lanes
#pragma unroll
  for (int s = 1; s < 64; s <<= 1) {
    float p0 = __shfl_xor(F0, s), p1 = __shfl_xor(F1, s), p2 = __shfl_xor(F2, s),
          p3 = __shfl_xor(F3, s), p4 = __shfl_xor(F4, s);
    SINS5(F0, F1, F2, F3, F4, p0);
    SINS5(F0, F1, F2, F3, F4, p1);
    SINS5(F0, F1, F2, F3, F4, p2);
    SINS5(F0, F1, F2, F3, F4, p3);
    SINS5(F0, F1, F2, F3, F4, p4);
  }
  if (l == 0) {
    float q2v = q2[q];
    float s = sqrtf(fmaxf(q2v + F0, 1e-12f)) + sqrtf(fmaxf(q2v + F1, 1e-12f)) +
              sqrtf(fmaxf(q2v + F2, 1e-12f)) + sqrtf(fmaxf(q2v + F3, 1e-12f)) +
              sqrtf(fmaxf(q2v + F4, 1e-12f));
    scores[q] = s * 0.2f;
  }
}

// ---------- half-pixel bilinear 32x32 -> 512x512 (clamped == jax renorm) ----------
__global__ __launch_bounds__(256) void resize_kernel(const float* __restrict__ scores,
                                                     float* __restrict__ out) {
  int idx = blockIdx.x * 256 + threadIdx.x;
  int b = idx >> 18;
  int rem = idx & 262143;
  int oy = rem >> 9, ox = rem & 511;
  float sx = (ox + 0.5f) * 0.0625f - 0.5f;
  float sy = (oy + 0.5f) * 0.0625f - 0.5f;
  float fx0 = floorf(sx), fy0 = floorf(sy);
  int x0 = (int)fx0, y0 = (int)fy0;
  float fx = sx - fx0, fy = sy - fy0;
  int x0c = x0 < 0 ? 0 : (x0 > 31 ? 31 : x0);
  int x1c = (x0 + 1) < 0 ? 0 : ((x0 + 1) > 31 ? 31 : (x0 + 1));
  int y0c = y0 < 0 ? 0 : (y0 > 31 ? 31 : y0);
  int y1c = (y0 + 1) < 0 ? 0 : ((y0 + 1) > 31 ? 31 : (y0 + 1));
  const float* sb = scores + (b << 10);
  float v00 = sb[y0c * 32 + x0c], v01 = sb[y0c * 32 + x1c];
  float v10 = sb[y1c * 32 + x0c], v11 = sb[y1c * 32 + x1c];
  float v0 = v00 + (v01 - v00) * fx;
  float v1 = v10 + (v11 - v10) * fx;
  out[idx] = v0 + (v1 - v0) * fy;
}

extern "C" void kernel_launch(void* const* d_in, const int* in_sizes, int n_in,
                              void* d_out, int out_size, void* d_ws, size_t ws_size,
                              hipStream_t stream) {
  const float* emb  = (const float*)d_in[0];   // [4,128,32,32]
  const float* bank = (const float*)d_in[1];   // [50000,128]
  float* out = (float*)d_out;                  // [4,1,512,512]
  char* ws = (char*)d_ws;

  u16*   bankbf = (u16*)(ws + WS_BANKBF);
  float* b2     = (float*)(ws + WS_B2);
  u16*   qbf    = (u16*)(ws + WS_QBF);
  float* q2     = (float*)(ws + WS_Q2);
  float* scores = (float*)(ws + WS_SCORES);
  void*  minbuf = (void*)(ws + WS_MINBUF);

  prep_bank<<<NPAD / 8, 256, 0, stream>>>(bank, bankbf, b2);
  prep_q<<<NQ / 256, 256, 0, stream>>>(emb, qbf, q2);
  if (ws_size >= (size_t)WS_NEED_F32) {
    pass1_kernel<true><<<32 * SEGS, 256, 0, stream>>>(bankbf, b2, qbf, minbuf);
    pass2_kernel<true><<<NQ / 4, 256, 0, stream>>>(bankbf, b2, qbf, q2, minbuf, scores);
  } else {
    pass1_kernel<false><<<32 * SEGS, 256, 0, stream>>>(bankbf, b2, qbf, minbuf);
    pass2_kernel<false><<<NQ / 4, 256, 0, stream>>>(bankbf, b2, qbf, q2, minbuf, scores);
  }
  resize_kernel<<<(NQ * 256) / 256, 256, 0, stream>>>(scores, out);
}

// Round 6
// 176.951 us; speedup vs baseline: 1.6354x; 1.6354x over previous
//
#include <hip/hip_runtime.h>

typedef unsigned short u16;
typedef __attribute__((ext_vector_type(4))) unsigned short u16x4;
typedef __attribute__((ext_vector_type(8))) unsigned short u16x8;
typedef __attribute__((ext_vector_type(8))) __bf16 bf16x8;
typedef __attribute__((ext_vector_type(4))) float f32x4;

#define N_BANK  50000
#define NPAD    50048      // 782 * 64
#define NCHUNKS 782        // 64-row chunks
#define SEGS    32         // 32 segments x <=25 strided chunks each
#define NCPAD   800        // 32 segs * 25 column slots
#define DIM     128
#define NQ      4096
#define CHUNK_B 16384      // 64 rows * 128 dims * 2B

// ---- workspace layout (byte offsets). minbuf mode gated on ws_size. ----
#define WS_BANKBF 0u          // NPAD*128*2  = 12,812,288
#define WS_B2     12812288u   // NPAD*4      =    200,192
#define WS_QBF    13012480u   // 4096*128*2  =  1,048,576
#define WS_Q2     14061056u   // 4096*4      =     16,384
#define WS_SCORES 14077440u   // 4096*4      =     16,384
#define WS_MINBUF 14093824u   // pairs u32 [4096][800] = 13,107,200 (end 27,201,024)
                              // single u16 [4096][800] =  6,553,600 (end 20,647,424)
#define WS_NEED_PAIRS 27201024u

__device__ __forceinline__ u16 f2bf(float f) {
  unsigned int x = __float_as_uint(f);
  x += 0x7fffu + ((x >> 16) & 1u);   // RNE to bf16
  return (u16)(x >> 16);
}
__device__ __forceinline__ u16 f2bf_up(float f) {  // round toward +inf (conservative min)
  unsigned int b = __float_as_uint(f);
  u16 h = (u16)(b >> 16);
  if (!(b >> 31) && (b & 0xffffu)) h++;
  return h;
}
__device__ __forceinline__ float bf2f(u16 h) {
  return __uint_as_float(((unsigned int)h) << 16);
}

// sorted-ascending top-5 insert, SAFE for x >= T4 (then it's a no-op).
#define SINS5(T0, T1, T2, T3, T4, x)                                  \
  {                                                                   \
    bool c3 = (x) < T3, c2 = (x) < T2, c1 = (x) < T1, c0 = (x) < T0;  \
    float nx_ = fminf((x), T4);                                       \
    T4 = c3 ? T3 : nx_;                                               \
    T3 = c3 ? (c2 ? T2 : (x)) : T3;                                   \
    T2 = c2 ? (c1 ? T1 : (x)) : T2;                                   \
    T1 = c1 ? (c0 ? T0 : (x)) : T1;                                   \
    T0 = c0 ? (x) : T0;                                               \
  }

__device__ __forceinline__ void gload_lds16(const void* g, void* l) {
  __builtin_amdgcn_global_load_lds(
      (const __attribute__((address_space(1))) void*)g,
      (__attribute__((address_space(3))) void*)l, 16, 0, 0);
}

// ---------- prep: bank -> bf16 (+ pad rows), b2 = ||b||^2 (pad = 1e30) ----------
__global__ __launch_bounds__(256) void prep_bank(const float* __restrict__ bank,
                                                 u16* __restrict__ bb,
                                                 float* __restrict__ b2) {
  int row = blockIdx.x * 8 + (threadIdx.x >> 5);
  int cc  = threadIdx.x & 31;
  bool valid = row < N_BANK;
  f32x4 v = f32x4{0.f, 0.f, 0.f, 0.f};
  if (valid) v = *reinterpret_cast<const f32x4*>(bank + (size_t)row * DIM + cc * 4);
  float s = v.x * v.x + v.y * v.y + v.z * v.z + v.w * v.w;
#pragma unroll
  for (int o = 16; o > 0; o >>= 1) s += __shfl_xor(s, o, 32);
  u16x4 u;
  u.x = f2bf(v.x); u.y = f2bf(v.y); u.z = f2bf(v.z); u.w = f2bf(v.w);
  *reinterpret_cast<u16x4*>(bb + (size_t)row * DIM + cc * 4) = u;
  if (cc == 0) b2[row] = valid ? s : 1e30f;
}

// ---------- prep: embeddings [4,128,32,32] -> q_bf16 [4096][128], q2 ----------
__global__ __launch_bounds__(256) void prep_q(const float* __restrict__ emb,
                                              u16* __restrict__ qb,
                                              float* __restrict__ q2) {
  int q = blockIdx.x * 256 + threadIdx.x;
  int b = q >> 10, yx = q & 1023;
  const float* src = emb + (size_t)b * 131072 + yx;
  float s = 0.f;
#pragma unroll
  for (int d0 = 0; d0 < 16; ++d0) {
    u16x8 u;
#pragma unroll
    for (int j = 0; j < 8; ++j) {
      float v = src[(d0 * 8 + j) * 1024];
      s += v * v;
      u[j] = f2bf(v);
    }
    *reinterpret_cast<u16x8*>(qb + (size_t)q * DIM + d0 * 8) = u;
  }
  q2[q] = s;
}

// ---------- pass 1: GEMM + per-(query, chunk) top-2 of s = b2 - 2*dot ----------
// grid 512 = 16 qgroups (256 q) x 32 segments; 512 thr = 8 waves, wave owns 32 q.
// seg handles chunks c = seg + s*32 (s<25); results staged in LDS mintile and
// written TRANSPOSED minbuf[q][seg*25+s] with coalesced full-line stores.
template <bool PAIRS>
__global__ __launch_bounds__(512) void pass1_kernel(const u16* __restrict__ bankbf,
                                                    const float* __restrict__ b2,
                                                    const u16* __restrict__ qbf,
                                                    void* __restrict__ minbuf) {
  __shared__ char smc[2 * CHUNK_B];          // 32KB chunk double buffer
  __shared__ unsigned int mintile[6400];     // 25.6KB: [256 q][25 cols]
  const int tid = threadIdx.x;
  const int w = tid >> 6, l = tid & 63;
  const int l15 = l & 15, lhi = l >> 4;
  const int qgi = blockIdx.x & 15, seg = blockIdx.x >> 4;
  const int qbase = qgi * 256 + w * 32;

  for (int i = tid; i < 6400; i += 512) mintile[i] = 0x7F807F80u;  // (+inf,+inf)

  bf16x8 bqA[4], bqB[4];
  {
    const u16* qa = qbf + (size_t)(qbase + l15) * DIM + lhi * 8;
#pragma unroll
    for (int kk = 0; kk < 4; ++kk) {
      bqA[kk] = *reinterpret_cast<const bf16x8*>(qa + kk * 32);
      bqB[kk] = *reinterpret_cast<const bf16x8*>(qa + 16 * DIM + kk * 32);
    }
  }

  auto stage = [&](int cc, int buf) {
    const char* gb = (const char*)bankbf + (size_t)cc * CHUNK_B;
#pragma unroll
    for (int i = 0; i < 2; ++i) {
      int x  = i * 8192 + tid * 16;
      int sx = x ^ (((x >> 8) & 7) << 4);    // XOR-swizzle on SOURCE, dest linear
      gload_lds16(gb + sx, smc + buf * CHUNK_B + i * 8192 + w * 1024);
    }
  };

  stage(seg, 0);
  __syncthreads();                           // also covers mintile init
  int cur = 0;
  int s = 0;
  for (int c = seg; c < NCHUNKS; c += SEGS, ++s) {
    if (c + SEGS < NCHUNKS) stage(c + SEGS, cur ^ 1);
    const char* sb = smc + cur * CHUNK_B;
    float m1A = 3e38f, m2A = 3e38f, m1B = 3e38f, m2B = 3e38f;
#pragma unroll
    for (int t = 0; t < 4; ++t) {
      f32x4 b2v = *reinterpret_cast<const f32x4*>(b2 + c * 64 + t * 16 + lhi * 4);
      bf16x8 af[4];
#pragma unroll
      for (int kk = 0; kk < 4; ++kk) {
        int p  = (t * 16 + l15) * 256 + kk * 64 + lhi * 16;
        int ph = p ^ (((p >> 8) & 7) << 4);  // swizzled read
        af[kk] = *reinterpret_cast<const bf16x8*>(sb + ph);
      }
      f32x4 accA = f32x4{0.f, 0.f, 0.f, 0.f};
      f32x4 accB = f32x4{0.f, 0.f, 0.f, 0.f};
#pragma unroll
      for (int kk = 0; kk < 4; ++kk) {
        accA = __builtin_amdgcn_mfma_f32_16x16x32_bf16(af[kk], bqA[kk], accA, 0, 0, 0);
        accB = __builtin_amdgcn_mfma_f32_16x16x32_bf16(af[kk], bqB[kk], accB, 0, 0, 0);
      }
#pragma unroll
      for (int j = 0; j < 4; ++j) {
        float sA = fmaf(-2.f, accA[j], b2v[j]);
        float sB = fmaf(-2.f, accB[j], b2v[j]);
        if (PAIRS) {
          float t1 = fminf(m1A, sA);
          m2A = fminf(m2A, fmaxf(m1A, sA));
          m1A = t1;
          float t2 = fminf(m1B, sB);
          m2B = fminf(m2B, fmaxf(m1B, sB));
          m1B = t2;
        } else {
          m1A = fminf(m1A, sA);
          m1B = fminf(m1B, sB);
        }
      }
    }
    // pool the 4 row lane-groups per query (top-2 pair merge)
#pragma unroll
    for (int o = 16; o <= 32; o <<= 1) {
      float o1 = __shfl_xor(m1A, o);
      if (PAIRS) {
        float o2 = __shfl_xor(m2A, o);
        m2A = fminf(fminf(m2A, o2), fmaxf(m1A, o1));
      }
      m1A = fminf(m1A, o1);
      float p1 = __shfl_xor(m1B, o);
      if (PAIRS) {
        float p2 = __shfl_xor(m2B, o);
        m2B = fminf(fminf(m2B, p2), fmaxf(m1B, p1));
      }
      m1B = fminf(m1B, p1);
    }
    if (l < 16) {
      unsigned int pA, pB;
      if (PAIRS) {
        pA = ((unsigned int)f2bf(m2A) << 16) | (unsigned int)f2bf(m1A);
        pB = ((unsigned int)f2bf(m2B) << 16) | (unsigned int)f2bf(m1B);
      } else {
        pA = f2bf_up(m1A);
        pB = f2bf_up(m1B);
      }
      mintile[(w * 32 + l) * 25 + s] = pA;
      mintile[(w * 32 + 16 + l) * 25 + s] = pB;
    }
    __syncthreads();
    cur ^= 1;
  }

  // coalesced transposed write-out: 256 q-rows x 25 contiguous columns
  if (PAIRS) {
    unsigned int* mb = (unsigned int*)minbuf;
    for (int i = tid; i < 6400; i += 512) {
      int qloc = i / 25, j = i - qloc * 25;
      mb[(size_t)(qgi * 256 + qloc) * NCPAD + seg * 25 + j] = mintile[i];
    }
  } else {
    u16* mb = (u16*)minbuf;
    for (int i = tid; i < 6400; i += 512) {
      int qloc = i / 25, j = i - qloc * 25;
      mb[(size_t)(qgi * 256 + qloc) * NCPAD + seg * 25 + j] = (u16)mintile[i];
    }
  }
}

// ---------- pass 2: per-query top-5 from stored chunk top-2; rare exact rescan ----------
// grid 1024 x 256: one wave per query; minbuf row is contiguous (coalesced).
template <bool PAIRS>
__global__ __launch_bounds__(256) void pass2_kernel(const u16* __restrict__ bankbf,
                                                    const float* __restrict__ b2,
                                                    const u16* __restrict__ qbf,
                                                    const float* __restrict__ q2,
                                                    const void* __restrict__ minbuf,
                                                    float* __restrict__ scores) {
  const int w = threadIdx.x >> 6, l = threadIdx.x & 63;
  const int q = blockIdx.x * 4 + w;

  unsigned int vals[13];
  if (PAIRS) {
    const unsigned int* row = (const unsigned int*)minbuf + (size_t)q * NCPAD;
#pragma unroll
    for (int r = 0; r < 13; ++r) {
      int col = r * 64 + l;
      vals[r] = (col < NCPAD) ? row[col] : 0x7F807F80u;
    }
  } else {
    const u16* row = (const u16*)minbuf + (size_t)q * NCPAD;
#pragma unroll
    for (int r = 0; r < 13; ++r) {
      int col = r * 64 + l;
      vals[r] = (col < NCPAD) ? (unsigned int)row[col] : 0x7F80u;
    }
  }

  // top-5 over all stored values
  float T0 = 3e38f, T1 = 3e38f, T2_ = 3e38f, T3 = 3e38f, T4 = 3e38f;
#pragma unroll
  for (int r = 0; r < 13; ++r) {
    float m1v = bf2f((u16)(vals[r] & 0xffffu));
    SINS5(T0, T1, T2_, T3, T4, m1v);
    if (PAIRS) {
      float m2v = bf2f((u16)(vals[r] >> 16));
      SINS5(T0, T1, T2_, T3, T4, m2v);
    }
  }
#pragma unroll
  for (int sft = 1; sft < 64; sft <<= 1) {
    float p0 = __shfl_xor(T0, sft), p1 = __shfl_xor(T1, sft), p2 = __shfl_xor(T2_, sft),
          p3 = __shfl_xor(T3, sft), p4 = __shfl_xor(T4, sft);
    SINS5(T0, T1, T2_, T3, T4, p0);
    SINS5(T0, T1, T2_, T3, T4, p1);
    SINS5(T0, T1, T2_, T3, T4, p2);
    SINS5(T0, T1, T2_, T3, T4, p3);
    SINS5(T0, T1, T2_, T3, T4, p4);
  }
  // PAIRS: slack covers bf16 RNE (<=1 ulp ~ 1.0 abs) both directions.
  // single: stored is rounded-up; rel 2^-8 + abs epsilon.
  const float thr = PAIRS ? (T4 + fabsf(T4) * 0.01f + 2.5f)
                          : (T4 + fabsf(T4) * 0.01f + 0.02f);

  float F0 = 3e38f, F1 = 3e38f, F2_ = 3e38f, F3 = 3e38f, F4 = 3e38f;
  unsigned long long msk[13];
  unsigned long long anym = 0ull;
#pragma unroll
  for (int r = 0; r < 13; ++r) {
    float m1v = bf2f((u16)(vals[r] & 0xffffu));
    bool flag;
    if (PAIRS) {
      float m2v = bf2f((u16)(vals[r] >> 16));
      flag = (m2v <= thr);     // chunk may hold a 3rd top-5 element -> exact rescan
      if (!flag) {             // unflagged contribute stored top-2 directly
        SINS5(F0, F1, F2_, F3, F4, m1v);
        SINS5(F0, F1, F2_, F3, F4, m2v);
      }
    } else {
      flag = (m1v <= thr);     // owner chunks all rescanned
    }
    msk[r] = __ballot(flag);
    anym |= msk[r];
  }

  if (anym) {
    u16x8 qu[16];
#pragma unroll
    for (int g = 0; g < 16; ++g)
      qu[g] = *reinterpret_cast<const u16x8*>(qbf + (size_t)q * DIM + g * 8);
    for (int r = 0; r < 13; ++r) {
      unsigned long long mset = msk[r];
      while (mset) {                   // wave-uniform candidate loop
        int bit = __ffsll((long long)mset) - 1;
        mset &= mset - 1;
        int col = r * 64 + bit;
        int sgi = col / 25, sj = col - sgi * 25;
        int chunk = sgi + sj * SEGS;   // column -> chunk id
        int rowid = chunk * 64 + l;    // 64 lanes = 64 rows of chunk
        const u16x8* bp = (const u16x8*)(bankbf + (size_t)rowid * DIM);
        float dot = 0.f;
#pragma unroll
        for (int g = 0; g < 16; ++g) {
          u16x8 bb = bp[g];
#pragma unroll
          for (int e = 0; e < 8; ++e)
            dot = fmaf(bf2f(bb[e]), bf2f(qu[g][e]), dot);
        }
        float d = fmaf(-2.f, dot, b2[rowid]);
        SINS5(F0, F1, F2_, F3, F4, d);
      }
    }
  }
#pragma unroll
  for (int sft = 1; sft < 64; sft <<= 1) {
    float p0 = __shfl_xor(F0, sft), p1 = __shfl_xor(F1, sft), p2 = __shfl_xor(F2_, sft),
          p3 = __shfl_xor(F3, sft), p4 = __shfl_xor(F4, sft);
    SINS5(F0, F1, F2_, F3, F4, p0);
    SINS5(F0, F1, F2_, F3, F4, p1);
    SINS5(F0, F1, F2_, F3, F4, p2);
    SINS5(F0, F1, F2_, F3, F4, p3);
    SINS5(F0, F1, F2_, F3, F4, p4);
  }
  if (l == 0) {
    float q2v = q2[q];
    float sc = sqrtf(fmaxf(q2v + F0, 1e-12f)) + sqrtf(fmaxf(q2v + F1, 1e-12f)) +
               sqrtf(fmaxf(q2v + F2_, 1e-12f)) + sqrtf(fmaxf(q2v + F3, 1e-12f)) +
               sqrtf(fmaxf(q2v + F4, 1e-12f));
    scores[q] = sc * 0.2f;
  }
}

// ---------- half-pixel bilinear 32x32 -> 512x512 (clamped == jax renorm) ----------
__global__ __launch_bounds__(256) void resize_kernel(const float* __restrict__ scores,
                                                     float* __restrict__ out) {
  int idx = blockIdx.x * 256 + threadIdx.x;
  int b = idx >> 18;
  int rem = idx & 262143;
  int oy = rem >> 9, ox = rem & 511;
  float sx = (ox + 0.5f) * 0.0625f - 0.5f;
  float sy = (oy + 0.5f) * 0.0625f - 0.5f;
  float fx0 = floorf(sx), fy0 = floorf(sy);
  int x0 = (int)fx0, y0 = (int)fy0;
  float fx = sx - fx0, fy = sy - fy0;
  int x0c = x0 < 0 ? 0 : (x0 > 31 ? 31 : x0);
  int x1c = (x0 + 1) < 0 ? 0 : ((x0 + 1) > 31 ? 31 : (x0 + 1));
  int y0c = y0 < 0 ? 0 : (y0 > 31 ? 31 : y0);
  int y1c = (y0 + 1) < 0 ? 0 : ((y0 + 1) > 31 ? 31 : (y0 + 1));
  const float* sb = scores + (b << 10);
  float v00 = sb[y0c * 32 + x0c], v01 = sb[y0c * 32 + x1c];
  float v10 = sb[y1c * 32 + x0c], v11 = sb[y1c * 32 + x1c];
  float v0 = v00 + (v01 - v00) * fx;
  float v1 = v10 + (v11 - v10) * fx;
  out[idx] = v0 + (v1 - v0) * fy;
}

extern "C" void kernel_launch(void* const* d_in, const int* in_sizes, int n_in,
                              void* d_out, int out_size, void* d_ws, size_t ws_size,
                              hipStream_t stream) {
  const float* emb  = (const float*)d_in[0];   // [4,128,32,32]
  const float* bank = (const float*)d_in[1];   // [50000,128]
  float* out = (float*)d_out;                  // [4,1,512,512]
  char* ws = (char*)d_ws;

  u16*   bankbf = (u16*)(ws + WS_BANKBF);
  float* b2     = (float*)(ws + WS_B2);
  u16*   qbf    = (u16*)(ws + WS_QBF);
  float* q2     = (float*)(ws + WS_Q2);
  float* scores = (float*)(ws + WS_SCORES);
  void*  minbuf = (void*)(ws + WS_MINBUF);

  prep_bank<<<NPAD / 8, 256, 0, stream>>>(bank, bankbf, b2);
  prep_q<<<NQ / 256, 256, 0, stream>>>(emb, qbf, q2);
  if (ws_size >= (size_t)WS_NEED_PAIRS) {
    pass1_kernel<true><<<16 * SEGS, 512, 0, stream>>>(bankbf, b2, qbf, minbuf);
    pass2_kernel<true><<<NQ / 4, 256, 0, stream>>>(bankbf, b2, qbf, q2, minbuf, scores);
  } else {
    pass1_kernel<false><<<16 * SEGS, 512, 0, stream>>>(bankbf, b2, qbf, minbuf);
    pass2_kernel<false><<<NQ / 4, 256, 0, stream>>>(bankbf, b2, qbf, q2, minbuf, scores);
  }
  resize_kernel<<<(NQ * 256) / 256, 256, 0, stream>>>(scores, out);
}

// Round 7
// 170.486 us; speedup vs baseline: 1.6974x; 1.0379x over previous
//
#include <hip/hip_runtime.h>

typedef unsigned short u16;
typedef __attribute__((ext_vector_type(4))) unsigned short u16x4;
typedef __attribute__((ext_vector_type(8))) unsigned short u16x8;
typedef __attribute__((ext_vector_type(8))) __bf16 bf16x8;
typedef __attribute__((ext_vector_type(4))) float f32x4;

#define N_BANK  50000
#define NPAD    50048      // 782 * 64
#define NCHUNKS 782        // 64-row chunks
#define SEGS    32         // 32 segments x <=25 strided chunks each
#define NCPAD   800        // 32 segs * 25 column slots
#define DIM     128
#define NQ      4096
#define CHUNK_B 16384      // 64 rows * 128 dims * 2B
#define NBANKBLK 6256      // prep: bank blocks (8 rows each)
#define NQBLK    64        // prep: query blocks (64 q each)

// ---- workspace layout (byte offsets). total 27,201,024 B (ws >= 27.7MB known) ----
#define WS_BANKBF 0u          // NPAD*128*2  = 12,812,288  (holds -2*bank in bf16)
#define WS_B2     12812288u   // NPAD*4      =    200,192
#define WS_QBF    13012480u   // 4096*128*2  =  1,048,576
#define WS_Q2     14061056u   // 4096*4      =     16,384
#define WS_SCORES 14077440u   // 4096*4      =     16,384
#define WS_MINBUF 14093824u   // pairs u32 [4096][800] = 13,107,200

__device__ __forceinline__ u16 f2bf(float f) {
  unsigned int x = __float_as_uint(f);
  x += 0x7fffu + ((x >> 16) & 1u);   // RNE to bf16
  return (u16)(x >> 16);
}
__device__ __forceinline__ float bf2f(u16 h) {
  return __uint_as_float(((unsigned int)h) << 16);
}

// sorted-ascending top-5 insert, SAFE for x >= T4 (then it's a no-op).
#define SINS5(T0, T1, T2, T3, T4, x)                                  \
  {                                                                   \
    bool c3 = (x) < T3, c2 = (x) < T2, c1 = (x) < T1, c0 = (x) < T0;  \
    float nx_ = fminf((x), T4);                                       \
    T4 = c3 ? T3 : nx_;                                               \
    T3 = c3 ? (c2 ? T2 : (x)) : T3;                                   \
    T2 = c2 ? (c1 ? T1 : (x)) : T2;                                   \
    T1 = c1 ? (c0 ? T0 : (x)) : T1;                                   \
    T0 = c0 ? (x) : T0;                                               \
  }

__device__ __forceinline__ void gload_lds16(const void* g, void* l) {
  __builtin_amdgcn_global_load_lds(
      (const __attribute__((address_space(1))) void*)g,
      (__attribute__((address_space(3))) void*)l, 16, 0, 0);
}

// ---------- fused prep: bank -> -2*bank bf16 + b2 ; emb -> q bf16 + q2 ----------
__global__ __launch_bounds__(256) void prep_kernel(const float* __restrict__ emb,
                                                   const float* __restrict__ bank,
                                                   u16* __restrict__ bb,
                                                   float* __restrict__ b2,
                                                   u16* __restrict__ qb,
                                                   float* __restrict__ q2) {
  const int tid = threadIdx.x;
  if (blockIdx.x < NBANKBLK) {
    int row = blockIdx.x * 8 + (tid >> 5);
    int cc  = tid & 31;
    bool valid = row < N_BANK;
    f32x4 v = f32x4{0.f, 0.f, 0.f, 0.f};
    if (valid) v = *reinterpret_cast<const f32x4*>(bank + (size_t)row * DIM + cc * 4);
    float s = v.x * v.x + v.y * v.y + v.z * v.z + v.w * v.w;
#pragma unroll
    for (int o = 16; o > 0; o >>= 1) s += __shfl_xor(s, o, 32);
    u16x4 u;                                  // store -2*bank (folds the -2 factor)
    u.x = f2bf(-2.f * v.x); u.y = f2bf(-2.f * v.y);
    u.z = f2bf(-2.f * v.z); u.w = f2bf(-2.f * v.w);
    *reinterpret_cast<u16x4*>(bb + (size_t)row * DIM + cc * 4) = u;
    if (cc == 0) b2[row] = valid ? s : 1e30f;
  } else {
    // 64 queries per block, 4-way d-split per query
    __shared__ float part[256];
    int qb0 = (blockIdx.x - NBANKBLK) * 64;
    int ql = tid & 63, p = tid >> 6;
    int q = qb0 + ql;
    int b = q >> 10, yx = q & 1023;
    const float* src = emb + (size_t)b * 131072 + (size_t)p * 32 * 1024 + yx;
    float s = 0.f;
#pragma unroll
    for (int d8 = 0; d8 < 4; ++d8) {
      u16x8 u;
#pragma unroll
      for (int j = 0; j < 8; ++j) {
        float v = src[(d8 * 8 + j) * 1024];
        s += v * v;
        u[j] = f2bf(v);
      }
      *reinterpret_cast<u16x8*>(qb + (size_t)q * DIM + p * 32 + d8 * 8) = u;
    }
    part[tid] = s;
    __syncthreads();
    if (p == 0) q2[q] = part[ql] + part[64 + ql] + part[128 + ql] + part[192 + ql];
  }
}

// ---------- pass 1: MFMA GEMM (C-init = b2, A = -2*bank) + per-chunk top-2 ----------
// grid 512 = 16 qgroups (256 q) x 32 segments; 256 thr = 4 waves, wave owns 64 q.
__global__ __launch_bounds__(256, 2) void pass1_kernel(const u16* __restrict__ bankbf,
                                                       const float* __restrict__ b2,
                                                       const u16* __restrict__ qbf,
                                                       unsigned int* __restrict__ minbuf) {
  __shared__ char smc[2 * CHUNK_B];          // 32KB chunk double buffer
  __shared__ unsigned int mintile[6400];     // 25.6KB: [256 q][25 cols]
  const int tid = threadIdx.x;
  const int w = tid >> 6, l = tid & 63;
  const int l15 = l & 15, lhi = l >> 4;
  const int qgi = blockIdx.x & 15, seg = blockIdx.x >> 4;
  const int qbase = qgi * 256 + w * 64;

  for (int i = tid; i < 6400; i += 256) mintile[i] = 0x7F807F80u;  // (+inf,+inf)

  // query B-fragments: 4 subgroups x 4 K-chunks, register-resident (64 VGPR)
  bf16x8 bq[16];
#pragma unroll
  for (int sg = 0; sg < 4; ++sg)
#pragma unroll
    for (int kk = 0; kk < 4; ++kk)
      bq[sg * 4 + kk] = *reinterpret_cast<const bf16x8*>(
          qbf + (size_t)(qbase + sg * 16 + l15) * DIM + kk * 32 + lhi * 8);

  // hoisted swizzled LDS read addresses (loop-invariant)
  int ph[16];
#pragma unroll
  for (int t = 0; t < 4; ++t)
#pragma unroll
    for (int kk = 0; kk < 4; ++kk) {
      int p = (t * 16 + l15) * 256 + kk * 64 + lhi * 16;
      ph[t * 4 + kk] = p ^ (((p >> 8) & 7) << 4);
    }

  auto stage = [&](int cc, int buf) {
    const char* gb = (const char*)bankbf + (size_t)cc * CHUNK_B;
#pragma unroll
    for (int i = 0; i < 4; ++i) {
      int x  = i * 4096 + tid * 16;
      int sx = x ^ (((x >> 8) & 7) << 4);    // XOR-swizzle on SOURCE, dest linear
      gload_lds16(gb + sx, smc + buf * CHUNK_B + i * 4096 + w * 1024);
    }
  };
  auto loadb2 = [&](int cc, f32x4* dst) {    // prefetched a full chunk ahead
#pragma unroll
    for (int t = 0; t < 4; ++t)
      dst[t] = *reinterpret_cast<const f32x4*>(b2 + cc * 64 + t * 16 + lhi * 4);
  };

  auto process = [&](const char* sb, const f32x4* bv, int s) {
    float m1[4], m2[4];
#pragma unroll
    for (int sg = 0; sg < 4; ++sg) { m1[sg] = 3e38f; m2[sg] = 3e38f; }
#pragma unroll
    for (int t = 0; t < 4; ++t) {
      bf16x8 af[4];
#pragma unroll
      for (int kk = 0; kk < 4; ++kk)
        af[kk] = *reinterpret_cast<const bf16x8*>(sb + ph[t * 4 + kk]);
      f32x4 acc[4];
#pragma unroll
      for (int sg = 0; sg < 4; ++sg) acc[sg] = bv[t];   // C-init = b2 (row-matched)
#pragma unroll
      for (int kk = 0; kk < 4; ++kk)
#pragma unroll
        for (int sg = 0; sg < 4; ++sg)
          acc[sg] = __builtin_amdgcn_mfma_f32_16x16x32_bf16(af[kk], bq[sg * 4 + kk],
                                                            acc[sg], 0, 0, 0);
      // acc == b2 - 2*dot directly; track top-2 per subgroup
#pragma unroll
      for (int sg = 0; sg < 4; ++sg)
#pragma unroll
        for (int j = 0; j < 4; ++j) {
          float sv = acc[sg][j];
          float t1 = fminf(m1[sg], sv);
          m2[sg] = fminf(m2[sg], fmaxf(m1[sg], sv));
          m1[sg] = t1;
        }
    }
    // pool the 4 row lane-groups per query; store bf16 pair
#pragma unroll
    for (int sg = 0; sg < 4; ++sg) {
#pragma unroll
      for (int o = 16; o <= 32; o <<= 1) {
        float o1 = __shfl_xor(m1[sg], o);
        float o2 = __shfl_xor(m2[sg], o);
        m2[sg] = fminf(fminf(m2[sg], o2), fmaxf(m1[sg], o1));
        m1[sg] = fminf(m1[sg], o1);
      }
      if (l < 16)
        mintile[(w * 64 + sg * 16 + l15) * 25 + s] =
            ((unsigned int)f2bf(m2[sg]) << 16) | (unsigned int)f2bf(m1[sg]);
    }
  };

  f32x4 b2A[4], b2B[4];
  stage(seg, 0);
  loadb2(seg, b2A);
  __syncthreads();

  int c = seg, s = 0;
  for (;;) {
    int c1 = c + SEGS;
    bool h1 = c1 < NCHUNKS;
    if (h1) { stage(c1, 1); loadb2(c1, b2B); }
    process(smc, b2A, s);
    __syncthreads();
    if (!h1) break;
    int c2 = c1 + SEGS;
    bool h2 = c2 < NCHUNKS;
    if (h2) { stage(c2, 0); loadb2(c2, b2A); }
    process(smc + CHUNK_B, b2B, s + 1);
    __syncthreads();
    if (!h2) break;
    c = c2; s += 2;
  }

  // coalesced transposed write-out: 256 q-rows x 25 contiguous columns
  for (int i = tid; i < 6400; i += 256) {
    int qloc = i / 25, j = i - qloc * 25;
    minbuf[(size_t)(qgi * 256 + qloc) * NCPAD + seg * 25 + j] = mintile[i];
  }
}

// ---------- pass 2: per-query top-5 from stored chunk top-2; rare exact rescan ----------
__global__ __launch_bounds__(256) void pass2_kernel(const u16* __restrict__ bankbf,
                                                    const float* __restrict__ b2,
                                                    const u16* __restrict__ qbf,
                                                    const float* __restrict__ q2,
                                                    const unsigned int* __restrict__ minbuf,
                                                    float* __restrict__ scores) {
  const int w = threadIdx.x >> 6, l = threadIdx.x & 63;
  const int q = blockIdx.x * 4 + w;

  unsigned int vals[13];
  {
    const unsigned int* row = minbuf + (size_t)q * NCPAD;
#pragma unroll
    for (int r = 0; r < 13; ++r) {
      int col = r * 64 + l;
      vals[r] = (col < NCPAD) ? row[col] : 0x7F807F80u;
    }
  }

  // top-5 over all stored values
  float T0 = 3e38f, T1 = 3e38f, T2_ = 3e38f, T3 = 3e38f, T4 = 3e38f;
#pragma unroll
  for (int r = 0; r < 13; ++r) {
    float m1v = bf2f((u16)(vals[r] & 0xffffu));
    float m2v = bf2f((u16)(vals[r] >> 16));
    SINS5(T0, T1, T2_, T3, T4, m1v);
    SINS5(T0, T1, T2_, T3, T4, m2v);
  }
#pragma unroll
  for (int sft = 1; sft < 64; sft <<= 1) {
    float p0 = __shfl_xor(T0, sft), p1 = __shfl_xor(T1, sft), p2 = __shfl_xor(T2_, sft),
          p3 = __shfl_xor(T3, sft), p4 = __shfl_xor(T4, sft);
    SINS5(T0, T1, T2_, T3, T4, p0);
    SINS5(T0, T1, T2_, T3, T4, p1);
    SINS5(T0, T1, T2_, T3, T4, p2);
    SINS5(T0, T1, T2_, T3, T4, p3);
    SINS5(T0, T1, T2_, T3, T4, p4);
  }
  // slack covers bf16 RNE of stored pairs both directions
  const float thr = T4 + fabsf(T4) * 0.01f + 2.5f;

  float F0 = 3e38f, F1 = 3e38f, F2_ = 3e38f, F3 = 3e38f, F4 = 3e38f;
  unsigned long long msk[13];
  unsigned long long anym = 0ull;
#pragma unroll
  for (int r = 0; r < 13; ++r) {
    float m1v = bf2f((u16)(vals[r] & 0xffffu));
    float m2v = bf2f((u16)(vals[r] >> 16));
    bool flag = (m2v <= thr);   // chunk may hold a 3rd top-5 element -> exact rescan
    if (!flag) {                // unflagged contribute stored top-2 directly
      SINS5(F0, F1, F2_, F3, F4, m1v);
      SINS5(F0, F1, F2_, F3, F4, m2v);
    }
    msk[r] = __ballot(flag);
    anym |= msk[r];
  }

  if (anym) {
    u16x8 qu[16];
#pragma unroll
    for (int g = 0; g < 16; ++g)
      qu[g] = *reinterpret_cast<const u16x8*>(qbf + (size_t)q * DIM + g * 8);
    for (int r = 0; r < 13; ++r) {
      unsigned long long mset = msk[r];
      while (mset) {                   // wave-uniform candidate loop
        int bit = __ffsll((long long)mset) - 1;
        mset &= mset - 1;
        int col = r * 64 + bit;
        int sgi = col / 25, sj = col - sgi * 25;
        int chunk = sgi + sj * SEGS;   // column -> chunk id
        int rowid = chunk * 64 + l;    // 64 lanes = 64 rows of chunk
        const u16x8* bp = (const u16x8*)(bankbf + (size_t)rowid * DIM);
        float dot = b2[rowid];         // bankbf holds -2*bank => d = b2 + sum
#pragma unroll
        for (int g = 0; g < 16; ++g) {
          u16x8 bb = bp[g];
#pragma unroll
          for (int e = 0; e < 8; ++e)
            dot = fmaf(bf2f(bb[e]), bf2f(qu[g][e]), dot);
        }
        SINS5(F0, F1, F2_, F3, F4, dot);
      }
    }
  }
#pragma unroll
  for (int sft = 1; sft < 64; sft <<= 1) {
    float p0 = __shfl_xor(F0, sft), p1 = __shfl_xor(F1, sft), p2 = __shfl_xor(F2_, sft),
          p3 = __shfl_xor(F3, sft), p4 = __shfl_xor(F4, sft);
    SINS5(F0, F1, F2_, F3, F4, p0);
    SINS5(F0, F1, F2_, F3, F4, p1);
    SINS5(F0, F1, F2_, F3, F4, p2);
    SINS5(F0, F1, F2_, F3, F4, p3);
    SINS5(F0, F1, F2_, F3, F4, p4);
  }
  if (l == 0) {
    float q2v = q2[q];
    float sc = sqrtf(fmaxf(q2v + F0, 1e-12f)) + sqrtf(fmaxf(q2v + F1, 1e-12f)) +
               sqrtf(fmaxf(q2v + F2_, 1e-12f)) + sqrtf(fmaxf(q2v + F3, 1e-12f)) +
               sqrtf(fmaxf(q2v + F4, 1e-12f));
    scores[q] = sc * 0.2f;
  }
}

// ---------- half-pixel bilinear 32x32 -> 512x512, float4 stores ----------
__global__ __launch_bounds__(256) void resize_kernel(const float* __restrict__ scores,
                                                     float* __restrict__ out) {
  int idx = blockIdx.x * 256 + threadIdx.x;        // 1024 blocks, 4 px per thread
  int b = idx >> 16;
  int rem = idx & 65535;
  int oy = rem >> 7, qx = rem & 127;
  float sy = (oy + 0.5f) * 0.0625f - 0.5f;
  float fy0 = floorf(sy);
  int y0 = (int)fy0;
  float fy = sy - fy0;
  int y0c = y0 < 0 ? 0 : (y0 > 31 ? 31 : y0);
  int y1c = (y0 + 1) < 0 ? 0 : ((y0 + 1) > 31 ? 31 : (y0 + 1));
  const float* sb = scores + (b << 10);
  const float* r0 = sb + y0c * 32;
  const float* r1 = sb + y1c * 32;
  f32x4 o;
#pragma unroll
  for (int k = 0; k < 4; ++k) {
    int ox = qx * 4 + k;
    float sx = (ox + 0.5f) * 0.0625f - 0.5f;
    float fx0 = floorf(sx);
    int x0 = (int)fx0;
    float fx = sx - fx0;
    int x0c = x0 < 0 ? 0 : (x0 > 31 ? 31 : x0);
    int x1c = (x0 + 1) < 0 ? 0 : ((x0 + 1) > 31 ? 31 : (x0 + 1));
    float v0 = r0[x0c] + (r0[x1c] - r0[x0c]) * fx;
    float v1 = r1[x0c] + (r1[x1c] - r1[x0c]) * fx;
    o[k] = v0 + (v1 - v0) * fy;
  }
  *reinterpret_cast<f32x4*>(out + ((size_t)b << 18) + oy * 512 + qx * 4) = o;
}

extern "C" void kernel_launch(void* const* d_in, const int* in_sizes, int n_in,
                              void* d_out, int out_size, void* d_ws, size_t ws_size,
                              hipStream_t stream) {
  const float* emb  = (const float*)d_in[0];   // [4,128,32,32]
  const float* bank = (const float*)d_in[1];   // [50000,128]
  float* out = (float*)d_out;                  // [4,1,512,512]
  char* ws = (char*)d_ws;

  u16*   bankbf = (u16*)(ws + WS_BANKBF);
  float* b2     = (float*)(ws + WS_B2);
  u16*   qbf    = (u16*)(ws + WS_QBF);
  float* q2     = (float*)(ws + WS_Q2);
  float* scores = (float*)(ws + WS_SCORES);
  unsigned int* minbuf = (unsigned int*)(ws + WS_MINBUF);

  prep_kernel<<<NBANKBLK + NQBLK, 256, 0, stream>>>(emb, bank, bankbf, b2, qbf, q2);
  pass1_kernel<<<16 * SEGS, 256, 0, stream>>>(bankbf, b2, qbf, minbuf);
  pass2_kernel<<<NQ / 4, 256, 0, stream>>>(bankbf, b2, qbf, q2, minbuf, scores);
  resize_kernel<<<(NQ * 256) / 1024, 256, 0, stream>>>(scores, out);
}